// Round 1
// baseline (415.067 us; speedup 1.0000x reference)
//
#include <hip/hip_runtime.h>
#include <hip/hip_bf16.h>
#include <cstdint>
#include <cstddef>

typedef __bf16 bf16_t;
typedef bf16_t bf16x8 __attribute__((ext_vector_type(8)));
typedef bf16_t bf16x4 __attribute__((ext_vector_type(4)));
typedef float f32x4 __attribute__((ext_vector_type(4)));

#define NB 8
#define NT 1024
#define NC 1024
#define NH 16
#define ND 64
#define NTP 64

// ---------------- cast fp32 -> bf16 (vectorized x4) ----------------
__global__ __launch_bounds__(256) void k_cast_bf16(const float* __restrict__ src,
                                                   bf16_t* __restrict__ dst, int n4) {
    int i = blockIdx.x * 256 + threadIdx.x;
    if (i < n4) {
        float4 f = ((const float4*)src)[i];
        bf16x4 o;
        o[0] = (bf16_t)f.x; o[1] = (bf16_t)f.y; o[2] = (bf16_t)f.z; o[3] = (bf16_t)f.w;
        ((bf16x4*)dst)[i] = o;
    }
}

// ---------------- transpose + cast: src (K,N) fp32 -> dst (N,K) bf16 ----------------
__global__ __launch_bounds__(256) void k_transpose_cast(const float* __restrict__ src,
                                                        bf16_t* __restrict__ dst,
                                                        int K, int N) {
    __shared__ float tile[32][33];
    int nt = blockIdx.x, kt = blockIdx.y;
    int tx = threadIdx.x & 31;
    int ty = threadIdx.x >> 5;  // 0..7
#pragma unroll
    for (int i = 0; i < 4; i++) {
        int r = ty + i * 8;
        tile[r][tx] = src[(size_t)(kt * 32 + r) * N + nt * 32 + tx];
    }
    __syncthreads();
#pragma unroll
    for (int i = 0; i < 4; i++) {
        int r = ty + i * 8;
        dst[(size_t)(nt * 32 + r) * K + kt * 32 + tx] = (bf16_t)tile[tx][r];
    }
}

// ---------------- GEMM: C(M,N) = A(M,K) @ BT(N,K)^T + bias ----------------
// 128x128 tile, BK=64, 256 threads (4 waves, 2x2), mfma_f32_16x16x32_bf16.
// LDS row stride 72 (pad 8) -> 2-way bank aliasing only (free per m136).
// M,N multiples of 128; K multiple of 64 (true for all calls here).
template <bool OUT_F32>
__global__ __launch_bounds__(256) void k_gemm_bt(const bf16_t* __restrict__ A,
                                                 const bf16_t* __restrict__ BT,
                                                 const float* __restrict__ bias,
                                                 void* __restrict__ Cout,
                                                 int M, int N, int K) {
    __shared__ bf16_t As[128 * 72];
    __shared__ bf16_t Bs[128 * 72];
    const int tid = threadIdx.x;
    const int lane = tid & 63;
    const int wave = tid >> 6;
    const int quad = lane >> 4;
    const int l15 = lane & 15;
    const int wm = (wave >> 1) * 64;
    const int wn = (wave & 1) * 64;
    const size_t rowA0 = (size_t)blockIdx.y * 128;
    const size_t colB0 = (size_t)blockIdx.x * 128;

    const f32x4 fz = {0.f, 0.f, 0.f, 0.f};
    f32x4 acc[4][4];
#pragma unroll
    for (int i = 0; i < 4; i++)
#pragma unroll
        for (int j = 0; j < 4; j++) acc[i][j] = fz;

    for (int k0 = 0; k0 < K; k0 += 64) {
        __syncthreads();
#pragma unroll
        for (int i = 0; i < 4; i++) {
            int c = tid + i * 256;       // 1024 chunks of 8 bf16
            int r = c >> 3;              // 0..127
            int kc = (c & 7) * 8;        // 0..56
            uint4 av = *(const uint4*)(A + (rowA0 + r) * K + k0 + kc);
            *(uint4*)(&As[r * 72 + kc]) = av;
            uint4 bv = *(const uint4*)(BT + (colB0 + r) * K + k0 + kc);
            *(uint4*)(&Bs[r * 72 + kc]) = bv;
        }
        __syncthreads();
#pragma unroll
        for (int kk = 0; kk < 2; kk++) {
            bf16x8 af[4], bfr[4];
#pragma unroll
            for (int i = 0; i < 4; i++)
                af[i] = *(const bf16x8*)(&As[(wm + i * 16 + l15) * 72 + kk * 32 + quad * 8]);
#pragma unroll
            for (int j = 0; j < 4; j++)
                bfr[j] = *(const bf16x8*)(&Bs[(wn + j * 16 + l15) * 72 + kk * 32 + quad * 8]);
#pragma unroll
            for (int i = 0; i < 4; i++)
#pragma unroll
                for (int j = 0; j < 4; j++)
                    acc[i][j] = __builtin_amdgcn_mfma_f32_16x16x32_bf16(af[i], bfr[j], acc[i][j], 0, 0, 0);
        }
    }
    // epilogue: C/D layout col=lane&15, row=quad*4+reg
#pragma unroll
    for (int i = 0; i < 4; i++) {
        size_t row = rowA0 + wm + i * 16 + quad * 4;
#pragma unroll
        for (int j = 0; j < 4; j++) {
            int col = (int)colB0 + wn + j * 16 + l15;
            float bv = bias[col];
#pragma unroll
            for (int r = 0; r < 4; r++) {
                float v = acc[i][j][r] + bv;
                if (OUT_F32)
                    ((float*)Cout)[(row + r) * (size_t)N + col] = v;
                else
                    ((bf16_t*)Cout)[(row + r) * (size_t)N + col] = (bf16_t)v;
            }
        }
    }
}

// ---------------- fused dual-softmax causal attention ----------------
// One block per (q-tile of 64, head, batch). qkv: (8192, 3072) bf16 [q|k|v],
// pqkv: (512, 3072) bf16. y: (8192, 1024) bf16.
// Main attention: online softmax over key tiles 0..qt (diag tile masked n>m).
// Prefix: one 64-key tile, separate softmax, masked n>m only when qt==0.
__global__ __launch_bounds__(256) void k_attn(const bf16_t* __restrict__ qkv,
                                              const bf16_t* __restrict__ pqkv,
                                              bf16_t* __restrict__ y) {
    const int qt = blockIdx.x;
    const int h = blockIdx.y;
    const int b = blockIdx.z;

    __shared__ bf16_t Qs[64 * 72];
    __shared__ bf16_t Ks[64 * 72];
    __shared__ bf16_t Vt[64 * 72];  // transposed: Vt[d][key]
    __shared__ bf16_t Ps[64 * 72];

    const int tid = threadIdx.x;
    const int lane = tid & 63;
    const int wave = tid >> 6;
    const int quad = lane >> 4;
    const int l15 = lane & 15;
    const float scale = 0.125f;  // 1/sqrt(64)

    const size_t qrow0 = (size_t)b * NT + (size_t)qt * 64;

    // load Q tile (64x64)
#pragma unroll
    for (int i = 0; i < 2; i++) {
        int c = tid + i * 256;
        int r = c >> 3;
        int cc = (c & 7) * 8;
        uint4 v = *(const uint4*)(qkv + (qrow0 + r) * 3072 + h * 64 + cc);
        *(uint4*)(&Qs[r * 72 + cc]) = v;
    }

    const f32x4 fz = {0.f, 0.f, 0.f, 0.f};
    float m_m[4], l_m[4], m_p[4], l_p[4];
    f32x4 Om[4], Op[4];
#pragma unroll
    for (int r = 0; r < 4; r++) { m_m[r] = -1e30f; l_m[r] = 0.f; m_p[r] = -1e30f; l_p[r] = 0.f; }
#pragma unroll
    for (int dj = 0; dj < 4; dj++) { Om[dj] = fz; Op[dj] = fz; }

    auto process = [&](bool diagMask, float* mr, float* lr, f32x4* O) {
        // S = Q @ K^T  (wave handles 16 q-rows x 64 keys)
        f32x4 S[4];
#pragma unroll
        for (int j = 0; j < 4; j++) S[j] = fz;
#pragma unroll
        for (int kk = 0; kk < 2; kk++) {
            bf16x8 aq = *(const bf16x8*)(&Qs[(wave * 16 + l15) * 72 + kk * 32 + quad * 8]);
#pragma unroll
            for (int j = 0; j < 4; j++) {
                bf16x8 bk = *(const bf16x8*)(&Ks[(j * 16 + l15) * 72 + kk * 32 + quad * 8]);
                S[j] = __builtin_amdgcn_mfma_f32_16x16x32_bf16(aq, bk, S[j], 0, 0, 0);
            }
        }
        // scale + mask + local row max
        float rmax[4];
#pragma unroll
        for (int r = 0; r < 4; r++) rmax[r] = -1e30f;
#pragma unroll
        for (int j = 0; j < 4; j++) {
            int n = j * 16 + l15;
#pragma unroll
            for (int r = 0; r < 4; r++) {
                float s = S[j][r] * scale;
                int m = wave * 16 + quad * 4 + r;
                if (diagMask && n > m) s = -1e30f;
                S[j][r] = s;
                rmax[r] = fmaxf(rmax[r], s);
            }
        }
        // row max across the 16-lane group (rows live in reg r, cols in l15)
#pragma unroll
        for (int r = 0; r < 4; r++) {
            float v = rmax[r];
#pragma unroll
            for (int off = 1; off < 16; off <<= 1) v = fmaxf(v, __shfl_xor(v, off, 64));
            rmax[r] = v;
        }
        float alpha[4];
#pragma unroll
        for (int r = 0; r < 4; r++) {
            float mn = fmaxf(mr[r], rmax[r]);
            alpha[r] = __expf(mr[r] - mn);
            mr[r] = mn;
        }
        // P = exp(S - m), row sums
        float rsum[4] = {0.f, 0.f, 0.f, 0.f};
#pragma unroll
        for (int j = 0; j < 4; j++) {
#pragma unroll
            for (int r = 0; r < 4; r++) {
                float p = __expf(S[j][r] - mr[r]);
                S[j][r] = p;
                rsum[r] += p;
            }
        }
#pragma unroll
        for (int r = 0; r < 4; r++) {
            float v = rsum[r];
#pragma unroll
            for (int off = 1; off < 16; off <<= 1) v += __shfl_xor(v, off, 64);
            lr[r] = lr[r] * alpha[r] + v;
        }
        // stage P -> LDS (C-layout write, A-layout read; wave-private rows)
#pragma unroll
        for (int j = 0; j < 4; j++)
#pragma unroll
            for (int r = 0; r < 4; r++)
                Ps[(wave * 16 + quad * 4 + r) * 72 + j * 16 + l15] = (bf16_t)S[j][r];
        // rescale O by alpha
#pragma unroll
        for (int dj = 0; dj < 4; dj++)
#pragma unroll
            for (int r = 0; r < 4; r++) O[dj][r] *= alpha[r];
        __syncthreads();
        // O += P @ V   (B operand from Vt[d][key], contiguous keys)
#pragma unroll
        for (int kk = 0; kk < 2; kk++) {
            bf16x8 ap = *(const bf16x8*)(&Ps[(wave * 16 + l15) * 72 + kk * 32 + quad * 8]);
#pragma unroll
            for (int dj = 0; dj < 4; dj++) {
                bf16x8 bv = *(const bf16x8*)(&Vt[(dj * 16 + l15) * 72 + kk * 32 + quad * 8]);
                O[dj] = __builtin_amdgcn_mfma_f32_16x16x32_bf16(ap, bv, O[dj], 0, 0, 0);
            }
        }
    };

    // ---- main attention over key tiles 0..qt ----
    for (int kt = 0; kt <= qt; kt++) {
        __syncthreads();  // protect Ks/Vt from overwrite while prior tile in use
        const size_t krow0 = (size_t)b * NT + (size_t)kt * 64;
#pragma unroll
        for (int i = 0; i < 2; i++) {
            int c = tid + i * 256;
            int r = c >> 3;
            int cc = (c & 7) * 8;
            uint4 kv = *(const uint4*)(qkv + (krow0 + r) * 3072 + NC + h * 64 + cc);
            *(uint4*)(&Ks[r * 72 + cc]) = kv;
            union { uint4 u; bf16_t e[8]; } vv;
            vv.u = *(const uint4*)(qkv + (krow0 + r) * 3072 + 2 * NC + h * 64 + cc);
#pragma unroll
            for (int e = 0; e < 8; e++) Vt[(cc + e) * 72 + r] = vv.e[e];
        }
        __syncthreads();
        process(kt == qt, m_m, l_m, Om);
    }

    // ---- prefix attention (separate softmax, one 64-key tile) ----
    __syncthreads();
    {
        const size_t prow0 = (size_t)b * NTP;
#pragma unroll
        for (int i = 0; i < 2; i++) {
            int c = tid + i * 256;
            int r = c >> 3;
            int cc = (c & 7) * 8;
            uint4 kv = *(const uint4*)(pqkv + (prow0 + r) * 3072 + NC + h * 64 + cc);
            *(uint4*)(&Ks[r * 72 + cc]) = kv;
            union { uint4 u; bf16_t e[8]; } vv;
            vv.u = *(const uint4*)(pqkv + (prow0 + r) * 3072 + 2 * NC + h * 64 + cc);
#pragma unroll
            for (int e = 0; e < 8; e++) Vt[(cc + e) * 72 + r] = vv.e[e];
        }
        __syncthreads();
        process(qt == 0, m_p, l_p, Op);
    }

    // ---- combine two normalized attentions, store y ----
#pragma unroll
    for (int dj = 0; dj < 4; dj++) {
#pragma unroll
        for (int r = 0; r < 4; r++) {
            float v = Om[dj][r] / l_m[r] + Op[dj][r] / l_p[r];
            y[(qrow0 + wave * 16 + quad * 4 + r) * NC + h * 64 + dj * 16 + l15] = (bf16_t)v;
        }
    }
}

// ---------------- launch ----------------
extern "C" void kernel_launch(void* const* d_in, const int* in_sizes, int n_in,
                              void* d_out, int out_size, void* d_ws, size_t ws_size,
                              hipStream_t stream) {
    (void)in_sizes; (void)n_in; (void)out_size; (void)ws_size;
    const float* x        = (const float*)d_in[0];
    const float* prefix   = (const float*)d_in[1];
    const float* w_attn   = (const float*)d_in[2];
    const float* b_attn   = (const float*)d_in[3];
    const float* w_prefix = (const float*)d_in[4];
    const float* b_prefix = (const float*)d_in[5];
    const float* w_proj   = (const float*)d_in[6];
    const float* b_proj   = (const float*)d_in[7];
    float* out = (float*)d_out;

    char* p = (char*)d_ws;
    auto carve = [&](size_t bytes) {
        char* q = p;
        p += (bytes + 255) & ~(size_t)255;
        return q;
    };
    bf16_t* xb   = (bf16_t*)carve((size_t)NB * NT * NC * 2);        // 16 MB
    bf16_t* pb   = (bf16_t*)carve((size_t)NB * NTP * NC * 2);       // 1 MB
    bf16_t* wTa  = (bf16_t*)carve((size_t)3 * NC * NC * 2);         // 6 MB
    bf16_t* wTp  = (bf16_t*)carve((size_t)3 * NC * NC * 2);         // 6 MB
    bf16_t* wTpr = (bf16_t*)carve((size_t)NC * NC * 2);             // 2 MB
    bf16_t* qkv  = (bf16_t*)carve((size_t)NB * NT * 3 * NC * 2);    // 48 MB
    bf16_t* pqkv = (bf16_t*)carve((size_t)NB * NTP * 3 * NC * 2);   // 3 MB
    bf16_t* yb   = (bf16_t*)carve((size_t)NB * NT * NC * 2);        // 16 MB

    // casts
    k_cast_bf16<<<(NB * NT * NC / 4 + 255) / 256, 256, 0, stream>>>(x, xb, NB * NT * NC / 4);
    k_cast_bf16<<<(NB * NTP * NC / 4 + 255) / 256, 256, 0, stream>>>(prefix, pb, NB * NTP * NC / 4);
    // weight transposes (to B^T bf16 layout)
    k_transpose_cast<<<dim3(3 * NC / 32, NC / 32), 256, 0, stream>>>(w_attn, wTa, NC, 3 * NC);
    k_transpose_cast<<<dim3(3 * NC / 32, NC / 32), 256, 0, stream>>>(w_prefix, wTp, NC, 3 * NC);
    k_transpose_cast<<<dim3(NC / 32, NC / 32), 256, 0, stream>>>(w_proj, wTpr, NC, NC);
    // qkv = x @ w_attn + b_attn  (bf16 out)
    k_gemm_bt<false><<<dim3(3 * NC / 128, NB * NT / 128), 256, 0, stream>>>(
        xb, wTa, b_attn, qkv, NB * NT, 3 * NC, NC);
    // pqkv = prefix @ w_prefix + b_prefix (bf16 out)
    k_gemm_bt<false><<<dim3(3 * NC / 128, NB * NTP / 128), 256, 0, stream>>>(
        pb, wTp, b_prefix, pqkv, NB * NTP, 3 * NC, NC);
    // attention
    k_attn<<<dim3(NT / 64, NH, NB), 256, 0, stream>>>(qkv, pqkv, yb);
    // out = y @ w_proj + b_proj (fp32 out)
    k_gemm_bt<true><<<dim3(NC / 128, NB * NT / 128), 256, 0, stream>>>(
        yb, wTpr, b_proj, out, NB * NT, NC, NC);
}